// Round 10
// baseline (1640.862 us; speedup 1.0000x reference)
//
#include <hip/hip_runtime.h>

#define N 100
#define NN (N * N)
#define LROW 128      // floats per row, paired layout: lds[i][2*(j&63) + (j>>6)]
#define HINF 1e9f

typedef unsigned long long ull;

__device__ __forceinline__ bool lanebit(ull m) {
#if __has_builtin(__builtin_amdgcn_inverse_ballot_w64)
    return __builtin_amdgcn_inverse_ballot_w64(m);
#else
    return (m >> (threadIdx.x & 63)) & 1ull;
#endif
}

// read element idx (0..127) of a value distributed as lane-owned pairs
__device__ __forceinline__ int rl2_i(int a, int b, int idx) {
    int lo = __builtin_amdgcn_readlane(a, idx & 63);
    int hi = __builtin_amdgcn_readlane(b, idx & 63);
    return (idx < 64) ? lo : hi;
}
__device__ __forceinline__ float rl2_f(float a, float b, int idx) {
    int lo = __builtin_amdgcn_readlane(__float_as_int(a), idx & 63);
    int hi = __builtin_amdgcn_readlane(__float_as_int(b), idx & 63);
    return __int_as_float((idx < 64) ? lo : hi);
}

// full-wave64 min via DPP (VALU-only), broadcast via readlane 63
__device__ __forceinline__ float wave_min_bcast(float x) {
    int v = __float_as_int(x);
#define STEP(ctrl)                                                                  \
    do {                                                                            \
        int t = __builtin_amdgcn_update_dpp(v, v, (ctrl), 0xF, 0xF, false);         \
        v = __float_as_int(fminf(__int_as_float(v), __int_as_float(t)));            \
    } while (0)
    STEP(0x111); STEP(0x112); STEP(0x114); STEP(0x118); STEP(0x142); STEP(0x143);
#undef STEP
    return __int_as_float(__builtin_amdgcn_readlane(v, 63));
}

// One block = one wave per batch element. Set-membership (used/intree) lives in
// wave-uniform 64-bit SGPR masks (SALU updates off the critical chain); used and
// invalid columns carry a decaying >=1e9 sentinel in minv, removing the INF
// cndmask from the chain. Both owned columns arrive in one ds_read_b64.
__global__ __launch_bounds__(64) void hungarian_kernel(
    const float* __restrict__ cost_all,
    const int* __restrict__ num_objects,
    float* __restrict__ out_mask,
    float* __restrict__ out_pred)
{
    __shared__ float c_lds[N * LROW];   // 51200 B
    __shared__ int   p_sh[N];

    const int b    = blockIdx.x;
    const int lane = threadIdx.x;
    const float* cost = cost_all + (size_t)b * NN;
    const int nobj = num_objects[b];

    // ---- stage cost into paired LDS layout, zeroing padding rows ----
    for (int f = lane * 4; f < NN; f += 256) {
        float4 vv = *reinterpret_cast<const float4*>(cost + f);
        float e[4] = {vv.x, vv.y, vv.z, vv.w};
#pragma unroll
        for (int k = 0; k < 4; ++k) {
            const int idx = f + k;
            const int i = idx / N;
            const int j = idx - i * N;
            c_lds[i * LROW + ((j & 63) << 1) + (j >> 6)] = (i < nobj) ? e[k] : 0.0f;
        }
    }
    __syncthreads();  // once; staging complete

    const float2* crow2 = reinterpret_cast<const float2*>(c_lds) + lane;  // lane's pair

    // distributed state: lane owns cols {lane, lane+64} and rows {lane, lane+64}
    float u_a = 0.f, u_b = 0.f;    // row potentials
    float v_a = 0.f, v_b = 0.f;    // col potentials
    int   p_a = -1,  p_b = -1;     // col -> matched row

    const ull invalid_b = ~((1ull << (N - 64)) - 1ull);  // cols >= 100 permanently used

    for (int r = 0; r < N; ++r) {
        float minv_a = HINF, minv_b = HINF;   // sentinel also for used/invalid cols
        int   way_a = -1, way_b = -1;
        ull used_a = 0, used_b = invalid_b;
        ull intree_a = 0, intree_b = 0;

        // ---- prologue: pending row = r ----
        int i0 = r, j0 = -1, jfin = -1;
        if (i0 < 64) intree_a = 1ull << i0; else intree_b = 1ull << (i0 - 64);
        float ui0 = rl2_f(u_a, u_b, i0);
        float2 c2 = crow2[i0 * (LROW / 2)];

        for (int it = 0; it < 128; ++it) {
            // relax from pending row (exact reference float-op order)
            const float cur_a = (c2.x - ui0) - v_a;
            const float cur_b = (c2.y - ui0) - v_b;
            const bool upd_a = !lanebit(used_a) && (cur_a < minv_a);
            const bool upd_b = !lanebit(used_b) && (cur_b < minv_b);
            minv_a = upd_a ? cur_a : minv_a;
            minv_b = upd_b ? cur_b : minv_b;
            way_a  = upd_a ? j0 : way_a;
            way_b  = upd_b ? j0 : way_b;

            const float delta = wave_min_bcast(fminf(minv_a, minv_b));

            // first index attaining the min (sentinels can never tie delta)
            const ull ba = __ballot(minv_a == delta);
            const ull bb = __ballot(minv_b == delta);
            const int j1 = (ba != 0ull) ? (__ffsll((long long)ba) - 1)
                                        : (64 + __ffsll((long long)bb) - 1);
            const int pj1 = rl2_i(p_a, p_b, j1);    // next row (or -1)

            // prefetch next row's pair immediately (clamped; cost is constant)
            const int inext = (pj1 < 0) ? 0 : pj1;
            const float2 c2n = crow2[inext * (LROW / 2)];

            // ---- dual updates in the LDS shadow (reference order per element) ----
            u_a = lanebit(intree_a) ? u_a + delta : u_a;
            u_b = lanebit(intree_b) ? u_b + delta : u_b;
            v_a = lanebit(used_a)   ? v_a - delta : v_a;
            v_b = lanebit(used_b)   ? v_b - delta : v_b;
            minv_a -= delta;                // unconditional; used lanes hold sentinel
            minv_b -= delta;
            minv_a = (j1 == lane)      ? HINF : minv_a;   // stomp selected col
            minv_b = (j1 == lane + 64) ? HINF : minv_b;
            if (j1 < 64) used_a |= 1ull << j1; else used_b |= 1ull << (j1 - 64);

            if (pj1 < 0) { jfin = j1; break; }   // reached a free column

            j0 = j1;
            if (pj1 < 64) intree_a |= 1ull << pj1; else intree_b |= 1ull << (pj1 - 64);
            ui0 = rl2_f(u_a, u_b, pj1);          // u[pj1] untouched this iter
            c2 = c2n;
        }

        // ---- augment: walk predecessor chain, flipping matches (register-only) ----
        int jj = jfin;
        for (int g = 0; g < N + 4 && jj >= 0; ++g) {
            const int w  = rl2_i(way_a, way_b, jj);
            const int pi = (w < 0) ? r : rl2_i(p_a, p_b, w);
            if (lane == (jj & 63)) {
                if (jj < 64) p_a = pi; else p_b = pi;
            }
            jj = w;
        }
    }

    // ---- outputs ----
    p_sh[lane] = p_a;
    if (lane + 64 < N) p_sh[lane + 64] = p_b;
    __syncthreads();

    float* mask = out_mask + (size_t)b * NN;
    for (int f = lane * 4; f < NN; f += 256) {
        float e[4];
#pragma unroll
        for (int k = 0; k < 4; ++k) {
            const int idx = f + k;
            const int i = idx / N;
            const int j = idx - i * N;
            e[k] = (p_sh[j] == i && i < nobj) ? 1.0f : 0.0f;
        }
        *reinterpret_cast<float4*>(mask + f) = make_float4(e[0], e[1], e[2], e[3]);
    }
    for (int j = lane; j < N; j += 64) {
        out_pred[(size_t)b * N + j] = (p_sh[j] < nobj) ? 1.0f : 0.0f;
    }
}

extern "C" void kernel_launch(void* const* d_in, const int* in_sizes, int n_in,
                              void* d_out, int out_size, void* d_ws, size_t ws_size,
                              hipStream_t stream) {
    const float* cost = (const float*)d_in[0];
    const int*   nobj = (const int*)d_in[1];
    float*       out  = (float*)d_out;
    const int B = in_sizes[1];                     // 256
    float* out_mask = out;                         // [B,100,100]
    float* out_pred = out + (size_t)B * N * N;     // [B,100,1]
    hipLaunchKernelGGL(hungarian_kernel, dim3(B), dim3(64), 0, stream,
                       cost, nobj, out_mask, out_pred);
}

// Round 15
// 1419.117 us; speedup vs baseline: 1.1563x; 1.1563x over previous
//
#include <hip/hip_runtime.h>

#define N 100
#define NN (N * N)
#define LROW 128      // floats per row, paired layout: lds[i][2*(j&63) + (j>>6)]
#define HINF 1e9f

typedef unsigned long long ull;

// per-lane select keyed directly off a wave-uniform 64-bit mask (1 VALU op)
__device__ __forceinline__ float csel_f(ull m, float t, float f) {
    float r;
    asm("v_cndmask_b32 %0, %1, %2, %3" : "=v"(r) : "v"(f), "v"(t), "s"(m));
    return r;
}
__device__ __forceinline__ int csel_i(ull m, int t, int f) {
    int r;
    asm("v_cndmask_b32 %0, %1, %2, %3" : "=v"(r) : "v"(f), "v"(t), "s"(m));
    return r;
}
__device__ __forceinline__ ull vcmp_lt_f(float a, float b) {
    ull m;
    asm("v_cmp_lt_f32 %0, %1, %2" : "=s"(m) : "v"(a), "v"(b));
    return m;
}
__device__ __forceinline__ ull vcmp_eq_fs(float v, float s) {  // lanes where v == uniform s
    ull m;
    asm("v_cmp_eq_f32 %0, %1, %2" : "=s"(m) : "v"(v), "s"(s));
    return m;
}

__device__ __forceinline__ float rl2_f(float a, float b, int idx) {
    int lo = __builtin_amdgcn_readlane(__float_as_int(a), idx & 63);
    int hi = __builtin_amdgcn_readlane(__float_as_int(b), idx & 63);
    return __int_as_float((idx < 64) ? lo : hi);
}
__device__ __forceinline__ int rl2_i(int a, int b, int idx) {
    int lo = __builtin_amdgcn_readlane(a, idx & 63);
    int hi = __builtin_amdgcn_readlane(b, idx & 63);
    return (idx < 64) ? lo : hi;
}

// full-wave64 min via DPP, broadcast via readlane 63 (uniform result -> SGPR)
__device__ __forceinline__ float wave_min_bcast(float x) {
    int v = __float_as_int(x);
#define STEP(ctrl)                                                                  \
    do {                                                                            \
        int t = __builtin_amdgcn_update_dpp(v, v, (ctrl), 0xF, 0xF, false);         \
        v = __float_as_int(fminf(__int_as_float(v), __int_as_float(t)));            \
    } while (0)
    STEP(0x111); STEP(0x112); STEP(0x114); STEP(0x118); STEP(0x142); STEP(0x143);
#undef STEP
    return __int_as_float(__builtin_amdgcn_readlane(v, 63));
}

// One block = one wave per batch element. used/intree as wave-uniform SGPR
// masks consumed ONLY via v_cndmask-with-sgpr-pair (no per-lane mask shifts);
// p packed 16-bit (one readlane + scalar extract on chain); eq-compare straight
// against the SGPR delta; SALU row addressing; both owned cols in one ds_read_b64.
__global__ __launch_bounds__(64) void hungarian_kernel(
    const float* __restrict__ cost_all,
    const int* __restrict__ num_objects,
    float* __restrict__ out_mask,
    float* __restrict__ out_pred)
{
    __shared__ float c_lds[N * LROW];   // 51200 B
    __shared__ int   p_sh[N];

    const int b    = blockIdx.x;
    const int lane = threadIdx.x;
    const float* cost = cost_all + (size_t)b * NN;
    const int nobj = num_objects[b];

    // ---- stage cost into paired LDS layout, zeroing padding rows ----
    for (int f = lane * 4; f < NN; f += 256) {
        float4 vv = *reinterpret_cast<const float4*>(cost + f);
        float e[4] = {vv.x, vv.y, vv.z, vv.w};
#pragma unroll
        for (int k = 0; k < 4; ++k) {
            const int idx = f + k;
            const int i = idx / N;
            const int j = idx - i * N;
            c_lds[i * LROW + ((j & 63) << 1) + (j >> 6)] = (i < nobj) ? e[k] : 0.0f;
        }
    }
    __syncthreads();  // once; staging complete

    const float2* crow2 = reinterpret_cast<const float2*>(c_lds) + lane;  // lane's pair

    // distributed state: lane owns cols {lane, lane+64}; u rows likewise
    float u_a = 0.f, u_b = 0.f;
    float v_a = 0.f, v_b = 0.f;
    int   p_pk = -1;               // packed: lo16 = p[lane], hi16 = p[lane+64]
    const float HV = HINF;

    const ull invalid_b = ~((1ull << (N - 64)) - 1ull);  // cols >= 100 permanently used

    for (int r = 0; r < N; ++r) {
        float minv_a = HINF, minv_b = HINF;   // sentinel for used/invalid cols
        int   way_a = -1, way_b = -1;
        ull used_a = 0, used_b = invalid_b;
        ull intree_a = 0, intree_b = 0;

        // ---- prologue: pending row = r ----
        int j0 = -1, jfin = -1;
        if (r < 64) intree_a = 1ull << r; else intree_b = 1ull << (r - 64);
        float ui0 = rl2_f(u_a, u_b, r);
        float2 c2 = crow2[r * (LROW / 2)];

        for (int it = 0; it < 128; ++it) {
            // relax from pending row (exact reference float-op order)
            const float cur_a = (c2.x - ui0) - v_a;
            const float cur_b = (c2.y - ui0) - v_b;
            const ull cc_a = vcmp_lt_f(cur_a, minv_a) & ~used_a;
            const ull cc_b = vcmp_lt_f(cur_b, minv_b) & ~used_b;
            minv_a = csel_f(cc_a, cur_a, minv_a);
            minv_b = csel_f(cc_b, cur_b, minv_b);
            way_a  = csel_i(cc_a, j0, way_a);
            way_b  = csel_i(cc_b, j0, way_b);

            const float delta = wave_min_bcast(fminf(minv_a, minv_b));  // SGPR

            // first index attaining the min (sentinels can never tie delta)
            const ull ba = vcmp_eq_fs(minv_a, delta);
            const ull bb = vcmp_eq_fs(minv_b, delta);
            const int j1 = (ba != 0ull) ? (int)__builtin_ctzll(ba)
                                        : 64 + (int)__builtin_ctzll(bb);

            // p[j1] via packed readlane + scalar extract
            const int ps  = __builtin_amdgcn_readlane(p_pk, j1 & 63);
            const int pj1 = (j1 < 64) ? (int)(short)(ps & 0xffff) : (ps >> 16);

            // issue next row's pair ASAP (clamped; cost is constant data)
            const int inext = (pj1 < 0) ? 0 : pj1;     // s_max
            const float2 c2n = crow2[inext * (LROW / 2)];

            // ---- dual updates in the LDS shadow (reference order per element) ----
            u_a = csel_f(intree_a, u_a + delta, u_a);
            u_b = csel_f(intree_b, u_b + delta, u_b);
            v_a = csel_f(used_a,   v_a - delta, v_a);   // used mask BEFORE j1 added
            v_b = csel_f(used_b,   v_b - delta, v_b);
            minv_a -= delta;               // unconditional; used lanes hold sentinel
            minv_b -= delta;
            const ull bit = 1ull << (j1 & 63);
            const ull bma = (j1 < 64) ? bit : 0ull;
            const ull bmb = (j1 < 64) ? 0ull : bit;
            minv_a = csel_f(bma, HV, minv_a);          // stomp selected col to sentinel
            minv_b = csel_f(bmb, HV, minv_b);
            used_a |= bma;
            used_b |= bmb;

            if (pj1 < 0) { jfin = j1; break; }         // reached a free column

            j0 = j1;
            if (pj1 < 64) intree_a |= 1ull << pj1; else intree_b |= 1ull << (pj1 - 64);
            ui0 = rl2_f(u_a, u_b, pj1);                // row pj1 untouched this iter
            c2 = c2n;
        }

        // ---- augment: walk predecessor chain, flipping matches ----
        int jj = jfin;
        for (int g = 0; g < N + 4 && jj >= 0; ++g) {
            const int w  = rl2_i(way_a, way_b, jj);
            const int ps = __builtin_amdgcn_readlane(p_pk, (w < 0 ? 0 : w) & 63);
            const int pw = (w < 64) ? (int)(short)(ps & 0xffff) : (ps >> 16);
            const int pi = (w < 0) ? r : pw;
            if (lane == (jj & 63)) {
                p_pk = (jj < 64) ? ((p_pk & 0xffff0000) | (pi & 0xffff))
                                 : ((p_pk & 0x0000ffff) | (pi << 16));
            }
            jj = w;
        }
    }

    // ---- outputs ----
    p_sh[lane] = (int)(short)(p_pk & 0xffff);
    if (lane + 64 < N) p_sh[lane + 64] = (p_pk >> 16);
    __syncthreads();

    float* mask = out_mask + (size_t)b * NN;
    for (int f = lane * 4; f < NN; f += 256) {
        float e[4];
#pragma unroll
        for (int k = 0; k < 4; ++k) {
            const int idx = f + k;
            const int i = idx / N;
            const int j = idx - i * N;
            e[k] = (p_sh[j] == i && i < nobj) ? 1.0f : 0.0f;
        }
        *reinterpret_cast<float4*>(mask + f) = make_float4(e[0], e[1], e[2], e[3]);
    }
    for (int j = lane; j < N; j += 64) {
        out_pred[(size_t)b * N + j] = (p_sh[j] < nobj) ? 1.0f : 0.0f;
    }
}

extern "C" void kernel_launch(void* const* d_in, const int* in_sizes, int n_in,
                              void* d_out, int out_size, void* d_ws, size_t ws_size,
                              hipStream_t stream) {
    const float* cost = (const float*)d_in[0];
    const int*   nobj = (const int*)d_in[1];
    float*       out  = (float*)d_out;
    const int B = in_sizes[1];                     // 256
    float* out_mask = out;                         // [B,100,100]
    float* out_pred = out + (size_t)B * N * N;     // [B,100,1]
    hipLaunchKernelGGL(hungarian_kernel, dim3(B), dim3(64), 0, stream,
                       cost, nobj, out_mask, out_pred);
}